// Round 1
// baseline (734.449 us; speedup 1.0000x reference)
//
#include <hip/hip_runtime.h>
#include <float.h>
#include <math.h>

#define BATCH 8
#define CHN   128
#define NPTS  2048
#define KNN   9
#define NOUT  256
#define TOTCNT (BATCH*NPTS*KNN)

__device__ __forceinline__ float dot4(float4 a, float4 b) {
    return a.x*b.x + a.y*b.y + a.z*b.z + a.w*b.w;
}

// ---------------- kernel 1: per-point squared norm ----------------
__global__ __launch_bounds__(256) void sq_kernel(const float* __restrict__ x,
                                                 float* __restrict__ sqg) {
    int i = blockIdx.x * 256 + threadIdx.x;      // 0..16383
    int b = i >> 11, n = i & (NPTS - 1);
    const float* xb = x + (size_t)b * CHN * NPTS + n;
    float s = 0.f;
#pragma unroll 8
    for (int c = 0; c < CHN; ++c) { float v = xb[c * NPTS]; s += v * v; }
    sqg[i] = s;
}

// ---------------- kernel 2: fused pairwise-dist + top-9 ----------------
// block: 256 threads, 64 queries. m-tiles of 64, K-chunks of 32.
// thread (ty,tx): micro-tile qi = 4*ty+i, mj = tx+16*j (strided to spread LDS banks)
__global__ __launch_bounds__(256) void knn_kernel(const float* __restrict__ x,
                                                  const float* __restrict__ sqg,
                                                  int* __restrict__ nn) {
    __shared__ __align__(16) float smem[15232];
    float* qt  = smem;            // 64 x 132 (padded)   33792 B
    float* mt  = smem + 8448;     // 64 x 36  (padded)    9216 B
    float* dt  = smem + 10752;    // 64 x 68  (padded)   17408 B
    float* sqq = smem + 15104;    // 64
    float* sqm = smem + 15168;    // 64

    const int b   = blockIdx.y;
    const int q0  = blockIdx.x * 64;
    const int tid = threadIdx.x;
    const float* xb = x + (size_t)b * CHN * NPTS;

    {   // load query tile (whole K=128), coalesced over n
        int qi = tid & 63, c0 = tid >> 6;
        for (int c = c0; c < CHN; c += 4)
            qt[qi * 132 + c] = xb[c * NPTS + q0 + qi];
        if (tid < 64) sqq[tid] = sqg[b * NPTS + q0 + tid];
    }

    const int ty = tid >> 4, tx = tid & 15;
    const int qs = tid >> 2, ss = tid & 3;   // scanner: 4 threads per query

    float dl[KNN]; int il[KNN];
#pragma unroll
    for (int k = 0; k < KNN; ++k) { dl[k] = FLT_MAX; il[k] = 0; }

    for (int m0 = 0; m0 < NPTS; m0 += 64) {
        if (tid < 64) sqm[tid] = sqg[b * NPTS + m0 + tid];
        float acc[4][4];
#pragma unroll
        for (int i = 0; i < 4; ++i)
#pragma unroll
            for (int j = 0; j < 4; ++j) acc[i][j] = 0.f;

        for (int chk = 0; chk < 4; ++chk) {
            __syncthreads();
            {   // load m-tile chunk (32 channels), coalesced over m
                int mj = tid & 63, cc0 = tid >> 6;
#pragma unroll
                for (int cc = cc0; cc < 32; cc += 4)
                    mt[mj * 36 + cc] = xb[(chk * 32 + cc) * NPTS + m0 + mj];
            }
            __syncthreads();
            for (int cc = 0; cc < 32; cc += 4) {
                float4 av[4], bv[4];
#pragma unroll
                for (int j = 0; j < 4; ++j)
                    av[j] = *(const float4*)&qt[(ty * 4 + j) * 132 + chk * 32 + cc];
#pragma unroll
                for (int j = 0; j < 4; ++j)
                    bv[j] = *(const float4*)&mt[(tx + 16 * j) * 36 + cc];
#pragma unroll
                for (int i = 0; i < 4; ++i)
#pragma unroll
                    for (int j = 0; j < 4; ++j)
                        acc[i][j] += dot4(av[i], bv[j]);
            }
        }
        // dist tile -> LDS
#pragma unroll
        for (int i = 0; i < 4; ++i)
#pragma unroll
            for (int j = 0; j < 4; ++j) {
                int qi2 = ty * 4 + i, mj2 = tx + 16 * j;
                dt[qi2 * 68 + mj2] = sqq[qi2] + sqm[mj2] - 2.f * acc[i][j];
            }
        __syncthreads();
        // each scanner thread: 16 candidates into its private sorted top-9
        for (int jj = 0; jj < 16; ++jj) {
            int ml = ss * 16 + jj;
            float v = dt[qs * 68 + ml];
            if (v < dl[KNN - 1]) {           // rare path
                int idx = m0 + ml;
                bool c0b = v < dl[0];
#pragma unroll
                for (int k = KNN - 1; k >= 1; --k) {
                    bool sh   = v < dl[k - 1];
                    bool here = v < dl[k];
                    float nd = sh ? dl[k - 1] : (here ? v : dl[k]);
                    int   ni = sh ? il[k - 1] : (here ? idx : il[k]);
                    dl[k] = nd; il[k] = ni;
                }
                if (c0b) { dl[0] = v; il[0] = idx; }
            }
        }
    }

    // merge the 4 scanners' sorted lists per query
    __syncthreads();
    float* md = smem + 8448;            // 64 x 36 floats (reuse mt)
    int*   mi = (int*)(smem + 10752);   // 64 x 36 ints   (reuse dt)
#pragma unroll
    for (int k = 0; k < KNN; ++k) {
        md[qs * 36 + ss * 9 + k] = dl[k];
        mi[qs * 36 + ss * 9 + k] = il[k];
    }
    __syncthreads();
    if (tid < 64) {
        int base = tid * 36;
        int p0 = 0, p1 = 0, p2 = 0, p3 = 0;
        int ob = (b * NPTS + q0 + tid) * KNN;
        for (int k = 0; k < KNN; ++k) {
            float v0 = (p0 < KNN) ? md[base + p0]      : FLT_MAX;
            float v1 = (p1 < KNN) ? md[base + 9 + p1]  : FLT_MAX;
            float v2 = (p2 < KNN) ? md[base + 18 + p2] : FLT_MAX;
            float v3 = (p3 < KNN) ? md[base + 27 + p3] : FLT_MAX;
            float best = v0; int sel = 0;
            if (v1 < best) { best = v1; sel = 1; }
            if (v2 < best) { best = v2; sel = 2; }
            if (v3 < best) { best = v3; sel = 3; }
            int idx;
            if      (sel == 0) { idx = mi[base + p0];      p0++; }
            else if (sel == 1) { idx = mi[base + 9 + p1];  p1++; }
            else if (sel == 2) { idx = mi[base + 18 + p2]; p2++; }
            else               { idx = mi[base + 27 + p3]; p3++; }
            nn[ob + k] = idx;
        }
    }
}

// ---------------- kernel 3: p = x·(W1-W2)^T, q = x·W2^T ----------------
// grid (32 ntiles, 4 otiles, 8 b); block 256; 64n x 64o tile; K-chunks of 32
__global__ __launch_bounds__(256) void pq_kernel(const float* __restrict__ x,
                                                 const float* __restrict__ W,
                                                 float* __restrict__ p,
                                                 float* __restrict__ q) {
    __shared__ __align__(16) float at[64 * 36];
    __shared__ __align__(16) float ut[64 * 36];
    __shared__ __align__(16) float vt[64 * 36];
    const int b = blockIdx.z, n0 = blockIdx.x * 64, o0 = blockIdx.y * 64;
    const float* xb = x + (size_t)b * CHN * NPTS;
    const int tid = threadIdx.x;
    const int ty = tid >> 4, tx = tid & 15;
    float accp[4][4] = {}, accq[4][4] = {};

    for (int chk = 0; chk < 4; ++chk) {
        __syncthreads();
        {
            int nn_ = tid & 63, cc0 = tid >> 6;
#pragma unroll
            for (int cc = cc0; cc < 32; cc += 4)
                at[nn_ * 36 + cc] = xb[(chk * 32 + cc) * NPTS + n0 + nn_];
            int cL = tid & 31, oo0 = tid >> 5;
#pragma unroll
            for (int oo = oo0; oo < 64; oo += 8) {
                float w1 = W[(o0 + oo) * 256 + chk * 32 + cL];
                float w2 = W[(o0 + oo) * 256 + 128 + chk * 32 + cL];
                ut[oo * 36 + cL] = w1 - w2;
                vt[oo * 36 + cL] = w2;
            }
        }
        __syncthreads();
        for (int cc = 0; cc < 32; cc += 4) {
            float4 av[4], uv[4], vv[4];
#pragma unroll
            for (int j = 0; j < 4; ++j) {
                av[j] = *(const float4*)&at[(ty * 4 + j) * 36 + cc];
                uv[j] = *(const float4*)&ut[(tx + 16 * j) * 36 + cc];
                vv[j] = *(const float4*)&vt[(tx + 16 * j) * 36 + cc];
            }
#pragma unroll
            for (int i = 0; i < 4; ++i)
#pragma unroll
                for (int j = 0; j < 4; ++j) {
                    accp[i][j] += dot4(av[i], uv[j]);
                    accq[i][j] += dot4(av[i], vv[j]);
                }
        }
    }
#pragma unroll
    for (int i = 0; i < 4; ++i)
#pragma unroll
        for (int j = 0; j < 4; ++j) {
            int n_ = n0 + ty * 4 + i, o_ = o0 + tx + 16 * j;
            size_t off = (size_t)(b * NPTS + n_) * NOUT + o_;
            p[off] = accp[i][j];
            q[off] = accq[i][j];
        }
}

// ---------------- kernel 4: BN statistics ----------------
// block handles 64 queries; thread = channel o; one atomic pair per (block, o)
__global__ __launch_bounds__(256) void stats_kernel(const float* __restrict__ p,
                                                    const float* __restrict__ q,
                                                    const int* __restrict__ nn,
                                                    float* __restrict__ stats) {
    const int b = blockIdx.y, n0 = blockIdx.x * 64;
    const int o = threadIdx.x;
    float s = 0.f, ss = 0.f;
    for (int qq = 0; qq < 64; ++qq) {
        int n_ = n0 + qq;
        float pv = p[(size_t)(b * NPTS + n_) * NOUT + o];
        const int* nr = nn + (b * NPTS + n_) * KNN;
#pragma unroll
        for (int k = 0; k < KNN; ++k) {
            float h = pv + q[(size_t)(b * NPTS + nr[k]) * NOUT + o];
            s += h; ss += h * h;
        }
    }
    atomicAdd(&stats[o], s);
    atomicAdd(&stats[NOUT + o], ss);
}

// ---------------- kernel 5: normalize + relu + max_k, transposed store ----------------
__global__ __launch_bounds__(256) void final_kernel(const float* __restrict__ p,
                                                    const float* __restrict__ q,
                                                    const int* __restrict__ nn,
                                                    const float* __restrict__ stats,
                                                    const float* __restrict__ gamma,
                                                    const float* __restrict__ beta,
                                                    float* __restrict__ out) {
    __shared__ float tr[256 * 17];
    const int b = blockIdx.y, n0 = blockIdx.x * 16;
    const int o = threadIdx.x;
    const float inv = 1.f / (float)TOTCNT;
    float mean = stats[o] * inv;
    float var  = stats[NOUT + o] * inv - mean * mean;
    float g    = gamma[o] / sqrtf(var + 1e-5f);
    float bet  = beta[o];
    for (int qq = 0; qq < 16; ++qq) {
        int n_ = n0 + qq;
        float pv = p[(size_t)(b * NPTS + n_) * NOUT + o];
        const int* nr = nn + (b * NPTS + n_) * KNN;
        float mx = 0.f;   // relu folded: max_k relu(h) = max(0, max_k h-norm)
#pragma unroll
        for (int k = 0; k < KNN; ++k) {
            float h  = pv + q[(size_t)(b * NPTS + nr[k]) * NOUT + o];
            float hn = (h - mean) * g + bet;
            mx = fmaxf(mx, hn);
        }
        tr[o * 17 + qq] = mx;
    }
    __syncthreads();
    int oo = threadIdx.x >> 4, qq = threadIdx.x & 15;
    for (int pass = 0; pass < 16; ++pass) {
        int o_ = pass * 16 + oo;
        out[((size_t)b * NOUT + o_) * NPTS + n0 + qq] = tr[o_ * 17 + qq];
    }
}

extern "C" void kernel_launch(void* const* d_in, const int* in_sizes, int n_in,
                              void* d_out, int out_size, void* d_ws, size_t ws_size,
                              hipStream_t stream) {
    (void)in_sizes; (void)n_in; (void)out_size; (void)ws_size;
    const float* x     = (const float*)d_in[0];
    const float* W     = (const float*)d_in[1];
    const float* gamma = (const float*)d_in[2];
    const float* beta  = (const float*)d_in[3];
    float* out = (float*)d_out;

    char* ws = (char*)d_ws;
    float* p     = (float*)ws;                                     // 16 MB
    float* q     = (float*)(ws + 16777216);                        // 16 MB
    float* sqg   = (float*)(ws + 2 * 16777216);                    // 64 KB
    float* stats = (float*)(ws + 2 * 16777216 + 65536);            // 2 KB
    int*   nn    = (int*)  (ws + 2 * 16777216 + 65536 + 4096);     // 576 KB

    hipMemsetAsync(stats, 0, 2 * NOUT * sizeof(float), stream);
    sq_kernel   <<<64, 256, 0, stream>>>(x, sqg);
    knn_kernel  <<<dim3(32, 8), 256, 0, stream>>>(x, sqg, nn);
    pq_kernel   <<<dim3(32, 4, 8), 256, 0, stream>>>(x, W, p, q);
    stats_kernel<<<dim3(32, 8), 256, 0, stream>>>(p, q, nn, stats);
    final_kernel<<<dim3(128, 8), 256, 0, stream>>>(p, q, nn, stats, gamma, beta, out);
}

// Round 2
// 313.313 us; speedup vs baseline: 2.3441x; 2.3441x over previous
//
#include <hip/hip_runtime.h>
#include <float.h>
#include <math.h>

#define BATCH 8
#define CHN   128
#define NPTS  2048
#define KNN   9
#define NOUT  256
#define TOTCNT (BATCH*NPTS*KNN)

typedef __attribute__((ext_vector_type(8))) short short8;
typedef __attribute__((ext_vector_type(4))) float f32x4;

__device__ __forceinline__ unsigned short f2bf(float f) {
    unsigned int u = __float_as_uint(f);
    unsigned int r = (u + 0x7FFFu + ((u >> 16) & 1u)) >> 16;
    return (unsigned short)r;
}
__device__ __forceinline__ float bf2f(unsigned short h) {
    return __uint_as_float(((unsigned int)h) << 16);
}
__device__ __forceinline__ float dot4(float4 a, float4 b) {
    return a.x*b.x + a.y*b.y + a.z*b.z + a.w*b.w;
}

// ---------------- kernel 1: transpose + bf16 split + squared norm ----------------
__global__ __launch_bounds__(256) void prep_kernel(const float* __restrict__ x,
                                                   unsigned short* __restrict__ xhi,
                                                   unsigned short* __restrict__ xlo,
                                                   float* __restrict__ sqg) {
    __shared__ float xt[128 * 65];
    __shared__ float psq[256];
    const int b = blockIdx.y, n0 = blockIdx.x * 64, tid = threadIdx.x;
#pragma unroll 4
    for (int p = 0; p < 32; ++p) {
        int c = p * 4 + (tid >> 6), n = tid & 63;
        xt[c * 65 + n] = x[((size_t)b * CHN + c) * NPTS + n0 + n];
    }
    __syncthreads();
    const int n = tid >> 2, cq = tid & 3;
    size_t row = (size_t)(b * NPTS + n0 + n) * CHN;
    float s = 0.f;
#pragma unroll 8
    for (int j = 0; j < 32; ++j) {
        int c = cq * 32 + j;
        float f = xt[c * 65 + n];
        unsigned short h = f2bf(f);
        float hf = bf2f(h);
        unsigned short l = f2bf(f - hf);
        xhi[row + c] = h;
        xlo[row + c] = l;
        s += f * f;
    }
    psq[tid] = s;
    __syncthreads();
    if (tid < 64)
        sqg[b * NPTS + n0 + tid] = psq[tid*4] + psq[tid*4+1] + psq[tid*4+2] + psq[tid*4+3];
}

// ---------------- kernel 2: MFMA split-bf16 distance + top-9 (per m-half) ----------------
// grid (32 qtiles, 2 m-halves, 8 b) = 512 blocks; block 256 = 4 waves.
// Block: 64 queries x 1024 m-range (4 iters of 256 m). Wave w owns m quadrant w*64.
__global__ __launch_bounds__(256, 2) void knn_mfma(const unsigned short* __restrict__ xhi,
                                                   const unsigned short* __restrict__ xlo,
                                                   const float* __restrict__ sqg,
                                                   float* __restrict__ pd,
                                                   int* __restrict__ pi) {
    __shared__ __align__(16) unsigned short qhs[64 * 40];   //  5120 B
    __shared__ __align__(16) unsigned short qls[64 * 40];   //  5120 B
    __shared__ __align__(16) unsigned short mhs[256 * 40];  // 20480 B
    __shared__ __align__(16) unsigned short mls[256 * 40];  // 20480 B
    __shared__ __align__(16) float dts[64 * 65];            // 16640 B
    __shared__ float sqq_s[64];
    __shared__ float sqm_s[256];

    const int tid = threadIdx.x;
    const int b = blockIdx.z, ms = blockIdx.y, q0 = blockIdx.x * 64;
    const int msbase = ms * 1024;
    const int wv = tid >> 6, lane = tid & 63;
    const int quad = lane >> 4, col = lane & 15;
    const int koff = quad * 8;
    const int wq = wv * 64;
    const size_t xb = (size_t)b * NPTS * CHN;

    if (tid < 64) sqq_s[tid] = sqg[b * NPTS + q0 + tid];

    float dl[KNN]; int il[KNN];
#pragma unroll
    for (int k = 0; k < KNN; ++k) { dl[k] = FLT_MAX; il[k] = 0; }

    const int qsc = tid >> 2, ss = tid & 3;   // scanner: 4 threads per query

    for (int iter = 0; iter < 4; ++iter) {
        const int mbase = msbase + iter * 256;
        f32x4 acc[4][4];
#pragma unroll
        for (int i = 0; i < 4; ++i)
#pragma unroll
            for (int j = 0; j < 4; ++j) acc[i][j] = (f32x4)0.f;

        for (int chk = 0; chk < 4; ++chk) {
            __syncthreads();
            if (chk == 0) sqm_s[tid] = sqg[b * NPTS + mbase + tid];
            {   // q chunk [64 q][32 c], padded stride 40
                int qr = tid & 63, seg = tid >> 6;
                size_t g = xb + (size_t)(q0 + qr) * CHN + chk * 32 + seg * 8;
                *(short8*)&qhs[qr * 40 + seg * 8] = *(const short8*)&xhi[g];
                *(short8*)&qls[qr * 40 + seg * 8] = *(const short8*)&xlo[g];
            }
            {   // m chunk [256 m][32 c], padded stride 40
                size_t g = xb + (size_t)(mbase + tid) * CHN + chk * 32;
#pragma unroll
                for (int j = 0; j < 4; ++j) {
                    *(short8*)&mhs[tid * 40 + j * 8] = *(const short8*)&xhi[g + j * 8];
                    *(short8*)&mls[tid * 40 + j * 8] = *(const short8*)&xlo[g + j * 8];
                }
            }
            __syncthreads();
            short8 ah[4], al[4], bh[4], bl[4];
#pragma unroll
            for (int i = 0; i < 4; ++i) {
                ah[i] = *(const short8*)&qhs[(i * 16 + col) * 40 + koff];
                al[i] = *(const short8*)&qls[(i * 16 + col) * 40 + koff];
            }
#pragma unroll
            for (int j = 0; j < 4; ++j) {
                bh[j] = *(const short8*)&mhs[(wq + j * 16 + col) * 40 + koff];
                bl[j] = *(const short8*)&mls[(wq + j * 16 + col) * 40 + koff];
            }
#pragma unroll
            for (int i = 0; i < 4; ++i)
#pragma unroll
                for (int j = 0; j < 4; ++j) {
                    acc[i][j] = __builtin_amdgcn_mfma_f32_16x16x32_bf16(ah[i], bh[j], acc[i][j], 0, 0, 0);
                    acc[i][j] = __builtin_amdgcn_mfma_f32_16x16x32_bf16(ah[i], bl[j], acc[i][j], 0, 0, 0);
                    acc[i][j] = __builtin_amdgcn_mfma_f32_16x16x32_bf16(al[i], bh[j], acc[i][j], 0, 0, 0);
                }
        }
        // selection: 4 phases, wave w2 dumps its 64x64 quadrant, all 256 threads scan
        for (int w2 = 0; w2 < 4; ++w2) {
            __syncthreads();
            if (wv == w2) {
#pragma unroll
                for (int i = 0; i < 4; ++i)
#pragma unroll
                    for (int j = 0; j < 4; ++j)
#pragma unroll
                        for (int r = 0; r < 4; ++r) {
                            int q_ = i * 16 + quad * 4 + r;
                            int m_ = j * 16 + col;
                            dts[q_ * 65 + m_] = sqq_s[q_] + sqm_s[wq + m_] - 2.f * acc[i][j][r];
                        }
            }
            __syncthreads();
            for (int jj = 0; jj < 16; ++jj) {
                int m_l = ss * 16 + jj;
                float v = dts[qsc * 65 + m_l];
                if (v < dl[KNN - 1]) {           // rare path
                    int idx = mbase + w2 * 64 + m_l;
                    bool c0b = v < dl[0];
#pragma unroll
                    for (int k = KNN - 1; k >= 1; --k) {
                        bool sh   = v < dl[k - 1];
                        bool here = v < dl[k];
                        float nd = sh ? dl[k - 1] : (here ? v : dl[k]);
                        int   ni = sh ? il[k - 1] : (here ? idx : il[k]);
                        dl[k] = nd; il[k] = ni;
                    }
                    if (c0b) { dl[0] = v; il[0] = idx; }
                }
            }
        }
    }

    // merge the 4 scanners' sorted lists per query; emit per-half top-9 with dists
    __syncthreads();
    float* md = dts;          // 64 x 36 floats (9216 B <= 16640)
    int*   mi = (int*)mhs;    // 64 x 36 ints   (9216 B <= 20480)
#pragma unroll
    for (int k = 0; k < KNN; ++k) {
        md[qsc * 36 + ss * 9 + k] = dl[k];
        mi[qsc * 36 + ss * 9 + k] = il[k];
    }
    __syncthreads();
    if (tid < 64) {
        int base = tid * 36;
        int p0 = 0, p1 = 0, p2 = 0, p3 = 0;
        size_t ob = ((size_t)(b * NPTS + q0 + tid) * 2 + ms) * KNN;
        for (int k = 0; k < KNN; ++k) {
            float v0 = (p0 < KNN) ? md[base + p0]      : FLT_MAX;
            float v1 = (p1 < KNN) ? md[base + 9 + p1]  : FLT_MAX;
            float v2 = (p2 < KNN) ? md[base + 18 + p2] : FLT_MAX;
            float v3 = (p3 < KNN) ? md[base + 27 + p3] : FLT_MAX;
            float best = v0; int sel = 0;
            if (v1 < best) { best = v1; sel = 1; }
            if (v2 < best) { best = v2; sel = 2; }
            if (v3 < best) { best = v3; sel = 3; }
            int idx;
            if      (sel == 0) { idx = mi[base + p0];      p0++; }
            else if (sel == 1) { idx = mi[base + 9 + p1];  p1++; }
            else if (sel == 2) { idx = mi[base + 18 + p2]; p2++; }
            else               { idx = mi[base + 27 + p3]; p3++; }
            pd[ob + k] = best;
            pi[ob + k] = idx;
        }
    }
}

// ---------------- kernel 3: merge the two m-half top-9 lists ----------------
__global__ __launch_bounds__(256) void merge2_kernel(const float* __restrict__ pd,
                                                     const int* __restrict__ pi,
                                                     int* __restrict__ nn) {
    int q = blockIdx.x * 256 + threadIdx.x;   // 0..16383
    const float* d0 = pd + (size_t)q * 18;
    const float* d1 = d0 + 9;
    const int*   i0 = pi + (size_t)q * 18;
    const int*   i1 = i0 + 9;
    int p0 = 0, p1 = 0;
#pragma unroll
    for (int k = 0; k < KNN; ++k) {
        float v0 = (p0 < KNN) ? d0[p0] : FLT_MAX;
        float v1 = (p1 < KNN) ? d1[p1] : FLT_MAX;
        if (v1 < v0) { nn[q * KNN + k] = i1[p1]; p1++; }
        else         { nn[q * KNN + k] = i0[p0]; p0++; }
    }
}

// ---------------- kernel 4: p = x·(W1-W2)^T, q = x·W2^T ----------------
__global__ __launch_bounds__(256) void pq_kernel(const float* __restrict__ x,
                                                 const float* __restrict__ W,
                                                 float* __restrict__ p,
                                                 float* __restrict__ q) {
    __shared__ __align__(16) float at[64 * 36];
    __shared__ __align__(16) float ut[64 * 36];
    __shared__ __align__(16) float vt[64 * 36];
    const int b = blockIdx.z, n0 = blockIdx.x * 64, o0 = blockIdx.y * 64;
    const float* xb = x + (size_t)b * CHN * NPTS;
    const int tid = threadIdx.x;
    const int ty = tid >> 4, tx = tid & 15;
    float accp[4][4] = {}, accq[4][4] = {};

    for (int chk = 0; chk < 4; ++chk) {
        __syncthreads();
        {
            int nn_ = tid & 63, cc0 = tid >> 6;
#pragma unroll
            for (int cc = cc0; cc < 32; cc += 4)
                at[nn_ * 36 + cc] = xb[(chk * 32 + cc) * NPTS + n0 + nn_];
            int cL = tid & 31, oo0 = tid >> 5;
#pragma unroll
            for (int oo = oo0; oo < 64; oo += 8) {
                float w1 = W[(o0 + oo) * 256 + chk * 32 + cL];
                float w2 = W[(o0 + oo) * 256 + 128 + chk * 32 + cL];
                ut[oo * 36 + cL] = w1 - w2;
                vt[oo * 36 + cL] = w2;
            }
        }
        __syncthreads();
        for (int cc = 0; cc < 32; cc += 4) {
            float4 av[4], uv[4], vv[4];
#pragma unroll
            for (int j = 0; j < 4; ++j) {
                av[j] = *(const float4*)&at[(ty * 4 + j) * 36 + cc];
                uv[j] = *(const float4*)&ut[(tx + 16 * j) * 36 + cc];
                vv[j] = *(const float4*)&vt[(tx + 16 * j) * 36 + cc];
            }
#pragma unroll
            for (int i = 0; i < 4; ++i)
#pragma unroll
                for (int j = 0; j < 4; ++j) {
                    accp[i][j] += dot4(av[i], uv[j]);
                    accq[i][j] += dot4(av[i], vv[j]);
                }
        }
    }
#pragma unroll
    for (int i = 0; i < 4; ++i)
#pragma unroll
        for (int j = 0; j < 4; ++j) {
            int n_ = n0 + ty * 4 + i, o_ = o0 + tx + 16 * j;
            size_t off = (size_t)(b * NPTS + n_) * NOUT + o_;
            p[off] = accp[i][j];
            q[off] = accq[i][j];
        }
}

// ---------------- kernel 5: BN statistics ----------------
__global__ __launch_bounds__(256) void stats_kernel(const float* __restrict__ p,
                                                    const float* __restrict__ q,
                                                    const int* __restrict__ nn,
                                                    float* __restrict__ stats) {
    const int b = blockIdx.y, n0 = blockIdx.x * 64;
    const int o = threadIdx.x;
    float s = 0.f, ss = 0.f;
    for (int qq = 0; qq < 64; ++qq) {
        int n_ = n0 + qq;
        float pv = p[(size_t)(b * NPTS + n_) * NOUT + o];
        const int* nr = nn + (b * NPTS + n_) * KNN;
#pragma unroll
        for (int k = 0; k < KNN; ++k) {
            float h = pv + q[(size_t)(b * NPTS + nr[k]) * NOUT + o];
            s += h; ss += h * h;
        }
    }
    atomicAdd(&stats[o], s);
    atomicAdd(&stats[NOUT + o], ss);
}

// ---------------- kernel 6: normalize + relu + max_k, transposed store ----------------
__global__ __launch_bounds__(256) void final_kernel(const float* __restrict__ p,
                                                    const float* __restrict__ q,
                                                    const int* __restrict__ nn,
                                                    const float* __restrict__ stats,
                                                    const float* __restrict__ gamma,
                                                    const float* __restrict__ beta,
                                                    float* __restrict__ out) {
    __shared__ float tr[256 * 17];
    const int b = blockIdx.y, n0 = blockIdx.x * 16;
    const int o = threadIdx.x;
    const float inv = 1.f / (float)TOTCNT;
    float mean = stats[o] * inv;
    float var  = stats[NOUT + o] * inv - mean * mean;
    float g    = gamma[o] / sqrtf(var + 1e-5f);
    float bet  = beta[o];
    for (int qq = 0; qq < 16; ++qq) {
        int n_ = n0 + qq;
        float pv = p[(size_t)(b * NPTS + n_) * NOUT + o];
        const int* nr = nn + (b * NPTS + n_) * KNN;
        float mx = 0.f;   // relu folded: max_k relu(h) = max(0, max_k h-norm)
#pragma unroll
        for (int k = 0; k < KNN; ++k) {
            float h  = pv + q[(size_t)(b * NPTS + nr[k]) * NOUT + o];
            float hn = (h - mean) * g + bet;
            mx = fmaxf(mx, hn);
        }
        tr[o * 17 + qq] = mx;
    }
    __syncthreads();
    int oo = threadIdx.x >> 4, qq = threadIdx.x & 15;
    for (int pass = 0; pass < 16; ++pass) {
        int o_ = pass * 16 + oo;
        out[((size_t)b * NOUT + o_) * NPTS + n0 + qq] = tr[o_ * 17 + qq];
    }
}

extern "C" void kernel_launch(void* const* d_in, const int* in_sizes, int n_in,
                              void* d_out, int out_size, void* d_ws, size_t ws_size,
                              hipStream_t stream) {
    (void)in_sizes; (void)n_in; (void)out_size; (void)ws_size;
    const float* x     = (const float*)d_in[0];
    const float* W     = (const float*)d_in[1];
    const float* gamma = (const float*)d_in[2];
    const float* beta  = (const float*)d_in[3];
    float* out = (float*)d_out;

    char* ws = (char*)d_ws;
    float*          p     = (float*)ws;                                   // 16 MB
    float*          q     = (float*)(ws + (16u << 20));                   // 16 MB
    unsigned short* xhi   = (unsigned short*)(ws + (32u << 20));          // 4 MB
    unsigned short* xlo   = (unsigned short*)(ws + (36u << 20));          // 4 MB
    float*          sqg   = (float*)(ws + (40u << 20));                   // 64 KB
    float*          stats = (float*)(ws + (40u << 20) + 65536);           // 2 KB (pad 4K)
    int*            nn    = (int*)  (ws + (40u << 20) + 65536 + 4096);    // 576 KB
    float*          pd    = (float*)(ws + (41u << 20));                   // 1.2 MB
    int*            pi    = (int*)  (ws + (43u << 20));                   // 1.2 MB

    hipMemsetAsync(stats, 0, 2 * NOUT * sizeof(float), stream);
    prep_kernel <<<dim3(32, 8),    256, 0, stream>>>(x, xhi, xlo, sqg);
    knn_mfma    <<<dim3(32, 2, 8), 256, 0, stream>>>(xhi, xlo, sqg, pd, pi);
    merge2_kernel<<<64,            256, 0, stream>>>(pd, pi, nn);
    pq_kernel   <<<dim3(32, 4, 8), 256, 0, stream>>>(x, W, p, q);
    stats_kernel<<<dim3(32, 8),    256, 0, stream>>>(p, q, nn, stats);
    final_kernel<<<dim3(128, 8),   256, 0, stream>>>(p, q, nn, stats, gamma, beta, out);
}

// Round 3
// 282.251 us; speedup vs baseline: 2.6021x; 1.1101x over previous
//
#include <hip/hip_runtime.h>
#include <float.h>
#include <math.h>

#define BATCH 8
#define CHN   128
#define NPTS  2048
#define KNN   9
#define NOUT  256
#define TOTCNT (BATCH*NPTS*KNN)

typedef __attribute__((ext_vector_type(8))) short short8;
typedef __attribute__((ext_vector_type(4))) float f32x4;

__device__ __forceinline__ unsigned short f2bf(float f) {
    unsigned int u = __float_as_uint(f);
    unsigned int r = (u + 0x7FFFu + ((u >> 16) & 1u)) >> 16;
    return (unsigned short)r;
}
__device__ __forceinline__ float bf2f(unsigned short h) {
    return __uint_as_float(((unsigned int)h) << 16);
}
__device__ __forceinline__ float dot4(float4 a, float4 b) {
    return a.x*b.x + a.y*b.y + a.z*b.z + a.w*b.w;
}

// ---------------- kernel 1: transpose + bf16 split + 0.5*squared-norm ----------------
__global__ __launch_bounds__(256) void prep_kernel(const float* __restrict__ x,
                                                   unsigned short* __restrict__ xhi,
                                                   unsigned short* __restrict__ xlo,
                                                   float* __restrict__ sqh) {
    __shared__ float xt[128 * 65];
    __shared__ float psq[256];
    const int b = blockIdx.y, n0 = blockIdx.x * 64, tid = threadIdx.x;
#pragma unroll 4
    for (int p = 0; p < 32; ++p) {
        int c = p * 4 + (tid >> 6), n = tid & 63;
        xt[c * 65 + n] = x[((size_t)b * CHN + c) * NPTS + n0 + n];
    }
    __syncthreads();
    const int n = tid >> 2, cq = tid & 3;
    size_t row = (size_t)(b * NPTS + n0 + n) * CHN;
    float s = 0.f;
#pragma unroll 8
    for (int j = 0; j < 32; ++j) {
        int c = cq * 32 + j;
        float f = xt[c * 65 + n];
        unsigned short h = f2bf(f);
        float hf = bf2f(h);
        unsigned short l = f2bf(f - hf);
        xhi[row + c] = h;
        xlo[row + c] = l;
        s += f * f;
    }
    psq[tid] = s;
    __syncthreads();
    if (tid < 64)
        sqh[b * NPTS + n0 + tid] =
            0.5f * (psq[tid*4] + psq[tid*4+1] + psq[tid*4+2] + psq[tid*4+3]);
}

// ---------------- kernel 2: MFMA split-bf16 distance + top-9 (per m-half) ----------------
// grid (32 qtiles, 2 m-halves, 8 b) = 512 blocks; block 256 = 4 waves.
// No LDS staging: MFMA fragments loaded directly from global (L1/L2-hot).
// Selection: all 4 waves dump 128-m half-tiles in parallel, 2 barriers per half.
__global__ __launch_bounds__(256, 3) void knn_mfma(const unsigned short* __restrict__ xhi,
                                                   const unsigned short* __restrict__ xlo,
                                                   const float* __restrict__ sqh,
                                                   float* __restrict__ pd,
                                                   int* __restrict__ pi) {
    __shared__ __align__(16) float dts[64 * 133];   // 34048 B; stride 133 spreads banks

    const int tid = threadIdx.x;
    const int b = blockIdx.z, ms = blockIdx.y, q0 = blockIdx.x * 64;
    const int msbase = ms * 1024;
    const int wv = tid >> 6, lane = tid & 63;
    const int quad = lane >> 4, col = lane & 15;
    const int koff = quad * 8;
    const int wq = wv * 64;
    const size_t xb = (size_t)b * NPTS * CHN;

    float dl[KNN]; int il[KNN];
#pragma unroll
    for (int k = 0; k < KNN; ++k) { dl[k] = FLT_MAX; il[k] = 0; }

    const int qsc = tid >> 2, ss = tid & 3;   // scanner: 4 threads per query

    for (int iter = 0; iter < 4; ++iter) {
        const int mbase = msbase + iter * 256;
        float sm[4];
#pragma unroll
        for (int j = 0; j < 4; ++j)
            sm[j] = sqh[b * NPTS + mbase + wq + j * 16 + col];

        f32x4 acc[4][4];
#pragma unroll
        for (int i = 0; i < 4; ++i)
#pragma unroll
            for (int j = 0; j < 4; ++j) acc[i][j] = (f32x4)0.f;

        for (int chk = 0; chk < 4; ++chk) {
            short8 ah[4], al[4];
#pragma unroll
            for (int i = 0; i < 4; ++i) {
                size_t g = xb + (size_t)(q0 + i * 16 + col) * CHN + chk * 32 + koff;
                ah[i] = *(const short8*)&xhi[g];
                al[i] = *(const short8*)&xlo[g];
            }
#pragma unroll
            for (int j = 0; j < 4; ++j) {
                size_t g = xb + (size_t)(mbase + wq + j * 16 + col) * CHN + chk * 32 + koff;
                short8 bh = *(const short8*)&xhi[g];
                short8 bl = *(const short8*)&xlo[g];
#pragma unroll
                for (int i = 0; i < 4; ++i) {
                    acc[i][j] = __builtin_amdgcn_mfma_f32_16x16x32_bf16(ah[i], bh, acc[i][j], 0, 0, 0);
                    acc[i][j] = __builtin_amdgcn_mfma_f32_16x16x32_bf16(ah[i], bl, acc[i][j], 0, 0, 0);
                    acc[i][j] = __builtin_amdgcn_mfma_f32_16x16x32_bf16(al[i], bh, acc[i][j], 0, 0, 0);
                }
            }
        }

        // selection in two 128-m halves; all waves dump their quadrant columns
        for (int half = 0; half < 2; ++half) {
            __syncthreads();   // previous scan (or previous iter) done with dts
#pragma unroll
            for (int jh = 0; jh < 2; ++jh) {
                int j = half * 2 + jh;
#pragma unroll
                for (int i = 0; i < 4; ++i)
#pragma unroll
                    for (int r = 0; r < 4; ++r) {
                        int q_ = i * 16 + quad * 4 + r;
                        dts[q_ * 133 + wv * 32 + jh * 16 + col] = sm[j] - acc[i][j][r];
                    }
            }
            __syncthreads();
            // scan: thread (qsc, ss) reads interleaved cols c = 4*jj + ss (2-way banks)
            for (int jj = 0; jj < 32; ++jj) {
                int c = jj * 4 + ss;
                float v = dts[qsc * 133 + c];
                if (v < dl[KNN - 1]) {           // rare path
                    int idx = mbase + half * 32 + (c & 31) + 2 * (c & 96);
                    bool c0b = v < dl[0];
#pragma unroll
                    for (int k = KNN - 1; k >= 1; --k) {
                        bool sh   = v < dl[k - 1];
                        bool here = v < dl[k];
                        float nd = sh ? dl[k - 1] : (here ? v : dl[k]);
                        int   ni = sh ? il[k - 1] : (here ? idx : il[k]);
                        dl[k] = nd; il[k] = ni;
                    }
                    if (c0b) { dl[0] = v; il[0] = idx; }
                }
            }
        }
    }

    // merge the 4 scanners' sorted lists per query; emit per-half top-9 with dists
    __syncthreads();
    float* md = dts;                    // 64 x 36 floats
    int*   mi = (int*)(dts + 2304);     // 64 x 36 ints
#pragma unroll
    for (int k = 0; k < KNN; ++k) {
        md[qsc * 36 + ss * 9 + k] = dl[k];
        mi[qsc * 36 + ss * 9 + k] = il[k];
    }
    __syncthreads();
    if (tid < 64) {
        int base = tid * 36;
        int p0 = 0, p1 = 0, p2 = 0, p3 = 0;
        size_t ob = ((size_t)(b * NPTS + q0 + tid) * 2 + ms) * KNN;
        for (int k = 0; k < KNN; ++k) {
            float v0 = (p0 < KNN) ? md[base + p0]      : FLT_MAX;
            float v1 = (p1 < KNN) ? md[base + 9 + p1]  : FLT_MAX;
            float v2 = (p2 < KNN) ? md[base + 18 + p2] : FLT_MAX;
            float v3 = (p3 < KNN) ? md[base + 27 + p3] : FLT_MAX;
            float best = v0; int sel = 0;
            if (v1 < best) { best = v1; sel = 1; }
            if (v2 < best) { best = v2; sel = 2; }
            if (v3 < best) { best = v3; sel = 3; }
            int idx;
            if      (sel == 0) { idx = mi[base + p0];      p0++; }
            else if (sel == 1) { idx = mi[base + 9 + p1];  p1++; }
            else if (sel == 2) { idx = mi[base + 18 + p2]; p2++; }
            else               { idx = mi[base + 27 + p3]; p3++; }
            pd[ob + k] = best;
            pi[ob + k] = idx;
        }
    }
}

// ---------------- kernel 3: merge the two m-half top-9 lists ----------------
__global__ __launch_bounds__(256) void merge2_kernel(const float* __restrict__ pd,
                                                     const int* __restrict__ pi,
                                                     int* __restrict__ nn) {
    int q = blockIdx.x * 256 + threadIdx.x;   // 0..16383
    const float* d0 = pd + (size_t)q * 18;
    const float* d1 = d0 + 9;
    const int*   i0 = pi + (size_t)q * 18;
    const int*   i1 = i0 + 9;
    int p0 = 0, p1 = 0;
#pragma unroll
    for (int k = 0; k < KNN; ++k) {
        float v0 = (p0 < KNN) ? d0[p0] : FLT_MAX;
        float v1 = (p1 < KNN) ? d1[p1] : FLT_MAX;
        if (v1 < v0) { nn[q * KNN + k] = i1[p1]; p1++; }
        else         { nn[q * KNN + k] = i0[p0]; p0++; }
    }
}

// ---------------- kernel 4: p = x·(W1-W2)^T, q = x·W2^T ----------------
__global__ __launch_bounds__(256) void pq_kernel(const float* __restrict__ x,
                                                 const float* __restrict__ W,
                                                 float* __restrict__ p,
                                                 float* __restrict__ q) {
    __shared__ __align__(16) float at[64 * 36];
    __shared__ __align__(16) float ut[64 * 36];
    __shared__ __align__(16) float vt[64 * 36];
    const int b = blockIdx.z, n0 = blockIdx.x * 64, o0 = blockIdx.y * 64;
    const float* xb = x + (size_t)b * CHN * NPTS;
    const int tid = threadIdx.x;
    const int ty = tid >> 4, tx = tid & 15;
    float accp[4][4] = {}, accq[4][4] = {};

    for (int chk = 0; chk < 4; ++chk) {
        __syncthreads();
        {
            int nn_ = tid & 63, cc0 = tid >> 6;
#pragma unroll
            for (int cc = cc0; cc < 32; cc += 4)
                at[nn_ * 36 + cc] = xb[(chk * 32 + cc) * NPTS + n0 + nn_];
            int cL = tid & 31, oo0 = tid >> 5;
#pragma unroll
            for (int oo = oo0; oo < 64; oo += 8) {
                float w1 = W[(o0 + oo) * 256 + chk * 32 + cL];
                float w2 = W[(o0 + oo) * 256 + 128 + chk * 32 + cL];
                ut[oo * 36 + cL] = w1 - w2;
                vt[oo * 36 + cL] = w2;
            }
        }
        __syncthreads();
        for (int cc = 0; cc < 32; cc += 4) {
            float4 av[4], uv[4], vv[4];
#pragma unroll
            for (int j = 0; j < 4; ++j) {
                av[j] = *(const float4*)&at[(ty * 4 + j) * 36 + cc];
                uv[j] = *(const float4*)&ut[(tx + 16 * j) * 36 + cc];
                vv[j] = *(const float4*)&vt[(tx + 16 * j) * 36 + cc];
            }
#pragma unroll
            for (int i = 0; i < 4; ++i)
#pragma unroll
                for (int j = 0; j < 4; ++j) {
                    accp[i][j] += dot4(av[i], uv[j]);
                    accq[i][j] += dot4(av[i], vv[j]);
                }
        }
    }
#pragma unroll
    for (int i = 0; i < 4; ++i)
#pragma unroll
        for (int j = 0; j < 4; ++j) {
            int n_ = n0 + ty * 4 + i, o_ = o0 + tx + 16 * j;
            size_t off = (size_t)(b * NPTS + n_) * NOUT + o_;
            p[off] = accp[i][j];
            q[off] = accq[i][j];
        }
}

// ---------------- kernel 5: BN statistics + per-(n,o) max/min ----------------
// Writes hmax in-place over p (each element read/written only by its own thread).
__global__ __launch_bounds__(256) void stats2_kernel(float* __restrict__ p,
                                                     const float* __restrict__ q,
                                                     const int* __restrict__ nn,
                                                     float* __restrict__ stats,
                                                     float* __restrict__ hmn) {
    __shared__ int idx_s[64 * KNN];
    const int b = blockIdx.y, n0 = blockIdx.x * 64;
    const int o = threadIdx.x;
    for (int t = threadIdx.x; t < 64 * KNN; t += 256)
        idx_s[t] = nn[(size_t)(b * NPTS + n0) * KNN + t];
    __syncthreads();
    const float* qb = q + (size_t)b * NPTS * NOUT + o;
    float s = 0.f, ss = 0.f;
    for (int qq = 0; qq < 64; ++qq) {
        size_t off = (size_t)(b * NPTS + n0 + qq) * NOUT + o;
        float pv = p[off];
        float h[KNN];
#pragma unroll
        for (int k = 0; k < KNN; ++k)
            h[k] = pv + qb[(size_t)idx_s[qq * KNN + k] * NOUT];
        float mx = h[0], mn = h[0];
#pragma unroll
        for (int k = 0; k < KNN; ++k) {
            s += h[k]; ss += h[k] * h[k];
            mx = fmaxf(mx, h[k]); mn = fminf(mn, h[k]);
        }
        p[off] = mx;
        hmn[off] = mn;
    }
    atomicAdd(&stats[o], s);
    atomicAdd(&stats[NOUT + o], ss);
}

// ---------------- kernel 6: normalize + relu + max_k, transposed store ----------------
__global__ __launch_bounds__(256) void final_kernel(const float* __restrict__ hmx,
                                                    const float* __restrict__ hmn,
                                                    const float* __restrict__ stats,
                                                    const float* __restrict__ gamma,
                                                    const float* __restrict__ beta,
                                                    float* __restrict__ out) {
    __shared__ float tr[256 * 17];
    const int b = blockIdx.y, n0 = blockIdx.x * 16;
    const int o = threadIdx.x;
    const float inv = 1.f / (float)TOTCNT;
    float mean = stats[o] * inv;
    float var  = stats[NOUT + o] * inv - mean * mean;
    float g    = gamma[o] / sqrtf(var + 1e-5f);
    float bet  = beta[o];
    for (int qq = 0; qq < 16; ++qq) {
        size_t off = (size_t)(b * NPTS + n0 + qq) * NOUT + o;
        float v = (g >= 0.f) ? hmx[off] : hmn[off];   // max of affine sits at hmax/hmin
        float hn = (v - mean) * g + bet;
        tr[o * 17 + qq] = fmaxf(hn, 0.f);
    }
    __syncthreads();
    int oo = threadIdx.x >> 4, qq = threadIdx.x & 15;
    for (int pass = 0; pass < 16; ++pass) {
        int o_ = pass * 16 + oo;
        out[((size_t)b * NOUT + o_) * NPTS + n0 + qq] = tr[o_ * 17 + qq];
    }
}

extern "C" void kernel_launch(void* const* d_in, const int* in_sizes, int n_in,
                              void* d_out, int out_size, void* d_ws, size_t ws_size,
                              hipStream_t stream) {
    (void)in_sizes; (void)n_in; (void)out_size; (void)ws_size;
    const float* x     = (const float*)d_in[0];
    const float* W     = (const float*)d_in[1];
    const float* gamma = (const float*)d_in[2];
    const float* beta  = (const float*)d_in[3];
    float* out = (float*)d_out;

    char* ws = (char*)d_ws;
    // [0,16M)  p  -> becomes hmax in stats2 (in-place)
    // [16,32M) q
    // [32,48M) knn scratch (xhi,xlo,pd,pi) -> dead by stats2 time, reused as hmn
    // [48M+)   sqh, stats, nn
    float*          p     = (float*)ws;
    float*          q     = (float*)(ws + (16u << 20));
    unsigned short* xhi   = (unsigned short*)(ws + (32u << 20));          // 4 MB
    unsigned short* xlo   = (unsigned short*)(ws + (36u << 20));          // 4 MB
    float*          pd    = (float*)(ws + (40u << 20));                   // 1.2 MB
    int*            pi    = (int*)  (ws + (42u << 20));                   // 1.2 MB
    float*          hmn   = (float*)(ws + (32u << 20));                   // 16 MB overlay
    float*          sqh   = (float*)(ws + (48u << 20));                   // 64 KB
    float*          stats = (float*)(ws + (48u << 20) + 65536);           // 2 KB (pad 4K)
    int*            nn    = (int*)  (ws + (48u << 20) + 65536 + 4096);    // 576 KB

    hipMemsetAsync(stats, 0, 2 * NOUT * sizeof(float), stream);
    prep_kernel  <<<dim3(32, 8),    256, 0, stream>>>(x, xhi, xlo, sqh);
    knn_mfma     <<<dim3(32, 2, 8), 256, 0, stream>>>(xhi, xlo, sqh, pd, pi);
    merge2_kernel<<<64,             256, 0, stream>>>(pd, pi, nn);
    pq_kernel    <<<dim3(32, 4, 8), 256, 0, stream>>>(x, W, p, q);
    stats2_kernel<<<dim3(32, 8),    256, 0, stream>>>(p, q, nn, stats, hmn);
    final_kernel <<<dim3(128, 8),   256, 0, stream>>>(p, hmn, stats, gamma, beta, out);
}